// Round 8
// baseline (280.177 us; speedup 1.0000x reference)
//
#include <hip/hip_runtime.h>
#include <hip/hip_fp16.h>

#define NN 50000
#define EE 800000
#define NB_E2 1563       // ceil(400000/256): 2 edges/thread grids
#define NWIN 8
#define WIN 6250         // node window (8 * 6250 = 50000)
#define NBUCK (NN * NWIN)  // 400000 counting-sort buckets: col*8 + row/WIN
#define EPB 1024         // edges per fill chunk (256 thr x 4)
#define NCHUNK 782       // ceil(800000/1024)
#define NSD 196          // ceil(50000/256) sd-finalize tail blocks
#define NSB 391          // ceil(400000/1024) scan blocks

// ---------------- bucket count + rank (bucket = col*8 + src window) ----------------
__global__ void k_count(const int* __restrict__ ei, int* cnt, int* __restrict__ rank) {
    int t = blockIdx.x * 256 + threadIdx.x;
    if (t < EE / 2) {
        int2 rr = *(const int2*)(ei + 2 * t);
        int2 cc = *(const int2*)(ei + EE + 2 * t);
        int b0 = cc.x * NWIN + rr.x / WIN;
        int b1 = cc.y * NWIN + rr.y / WIN;
        int r0 = atomicAdd(&cnt[b0], 1);
        int r1 = atomicAdd(&cnt[b1], 1);
        *(int2*)(rank + 2 * t) = make_int2(r0, r1);
    }
}

// ---------------- scan pass 1: per-block (1024) exclusive scan ----------------
__global__ __launch_bounds__(1024) void k_scan1(
    const int* __restrict__ cnt, int* sloc, int* bsum, int n) {
    __shared__ int s[1024];
    int tid = threadIdx.x;
    int i = blockIdx.x * 1024 + tid;
    int v = (i < n) ? cnt[i] : 0;
    s[tid] = v;
    __syncthreads();
    for (int off = 1; off < 1024; off <<= 1) {
        int t2 = 0;
        if (tid >= off) t2 = s[tid - off];
        __syncthreads();
        if (tid >= off) s[tid] += t2;
        __syncthreads();
    }
    if (i < n) sloc[i] = s[tid] - v;
    if (tid == 1023) bsum[blockIdx.x] = s[1023];
}

// ---------------- scan pass 2+3: block offset (redundant reduce) + finalize ----------------
__global__ __launch_bounds__(1024) void k_scan23(
    const int* __restrict__ sloc, const int* __restrict__ bsum,
    int* bstart, int n, int nb) {
    __shared__ int sb[1024];
    int tid = threadIdx.x, b = blockIdx.x;
    int v = (tid < nb && tid < b) ? bsum[tid] : 0;
    sb[tid] = v;
    __syncthreads();
    for (int off = 512; off; off >>= 1) {
        if (tid < off) sb[tid] += sb[tid + off];
        __syncthreads();
    }
    int boff = sb[0];
    int i = b * 1024 + tid;
    if (i < n) bstart[i] = sloc[i] + boff;
}

// ---------------- CSR fill (atomic-free, XCD-windowed by col) + sd/dis tail blocks ----------------
__global__ __launch_bounds__(256) void k_fill(
    const int* __restrict__ ei, const int* __restrict__ rank,
    const int* __restrict__ bstart, int* __restrict__ csr,
    int2* __restrict__ sd, float* __restrict__ dis)
{
    int b = blockIdx.x;
    if (b >= NCHUNK * 8) {  // tail: per-node sd + dis
        int i = (b - NCHUNK * 8) * 256 + threadIdx.x;
        if (i < NN) {
            int st = bstart[i * NWIN];
            int end = (i + 1 < NN) ? bstart[i * NWIN + NWIN] : EE;
            int deg = end - st;
            sd[i] = make_int2(st, deg);
            dis[i] = rsqrtf((float)deg + 1.0f);
        }
        return;
    }
    int w = b & 7;
    int chunk = b >> 3;
    int base = chunk * EPB + threadIdx.x * 4;
    int lo = w * WIN, hi = lo + WIN;
    if (base + 3 < EE) {
        int4 rr = *(const int4*)(ei + base);
        int4 cc = *(const int4*)(ei + EE + base);
        int4 rk = *(const int4*)(rank + base);
        if (cc.x >= lo && cc.x < hi) csr[bstart[cc.x * NWIN + rr.x / WIN] + rk.x] = rr.x;
        if (cc.y >= lo && cc.y < hi) csr[bstart[cc.y * NWIN + rr.y / WIN] + rk.y] = rr.y;
        if (cc.z >= lo && cc.z < hi) csr[bstart[cc.z * NWIN + rr.z / WIN] + rk.z] = rr.z;
        if (cc.w >= lo && cc.w < hi) csr[bstart[cc.w * NWIN + rr.w / WIN] + rk.w] = rr.w;
    } else {
        for (int e = 0; e < 4; e++) {
            int t = base + e;
            if (t < EE) {
                int c = ei[EE + t];
                int r = ei[t];
                if (c >= lo && c < hi) csr[bstart[c * NWIN + r / WIN] + rank[t]] = r;
            }
        }
    }
}

// ---------------- GEMM: LDS-staged x, thread-per-row, W via scalar cache ----------------
__global__ __launch_bounds__(256) void k_gemm(
    const float* __restrict__ x, const float* __restrict__ Wb,
    const float* __restrict__ Wc, const float* __restrict__ bc,
    const float* __restrict__ dis,
    __half* __restrict__ bsh, float* __restrict__ wcomb, int n)
{
    __shared__ float xt[32 * 257];  // transposed tile: xt[k][row]
    int tid = threadIdx.x;
    int grp = blockIdx.y;
    int row0 = blockIdx.x * 256;
    int row = row0 + tid;
    bool valid = row < n;

    const float* W = (grp < 2) ? (Wb + grp * 32) : Wc;
    const int ldw = (grp < 2) ? 64 : 32;

    float acc[32];
#pragma unroll
    for (int c = 0; c < 32; c++) acc[c] = 0.f;

    for (int s = 0; s < 4; s++) {
        int base_k = s * 32;
        float4 v[8];
#pragma unroll
        for (int i = 0; i < 8; i++) {
            int idx = i * 256 + tid;
            int r = idx >> 3;
            int k4 = idx & 7;
            int gr = row0 + r;
            v[i] = (gr < n) ? *(const float4*)(x + (size_t)gr * 128 + base_k + k4 * 4)
                            : make_float4(0.f, 0.f, 0.f, 0.f);
        }
        __syncthreads();
#pragma unroll
        for (int i = 0; i < 8; i++) {
            int idx = i * 256 + tid;
            int r = idx >> 3;
            int k4 = idx & 7;
            xt[(k4 * 4 + 0) * 257 + r] = v[i].x;
            xt[(k4 * 4 + 1) * 257 + r] = v[i].y;
            xt[(k4 * 4 + 2) * 257 + r] = v[i].z;
            xt[(k4 * 4 + 3) * 257 + r] = v[i].w;
        }
        __syncthreads();

        const float* Ws = W + base_k * ldw;
#pragma unroll 8
        for (int k = 0; k < 32; k++) {
            float xs = xt[k * 257 + tid];
            const float* wk = Ws + k * ldw;
#pragma unroll
            for (int c = 0; c < 32; c++) acc[c] = fmaf(xs, wk[c], acc[c]);
        }
    }

    if (!valid) return;
    if (grp < 2) {
        float d = dis[row];
        __half2 hh[16];
#pragma unroll
        for (int c = 0; c < 16; c++)
            hh[c] = __floats2half2_rn(acc[2 * c] * d, acc[2 * c + 1] * d);
        uint4* bo = (uint4*)(bsh + (size_t)row * 64 + grp * 32);
        const uint4* src = (const uint4*)hh;
#pragma unroll
        for (int c = 0; c < 4; c++) bo[c] = src[c];
    } else {
        float4* wo = (float4*)(wcomb + (size_t)row * 32);
#pragma unroll
        for (int c = 0; c < 8; c++)
            wo[c] = make_float4(acc[4*c] + bc[4*c], acc[4*c+1] + bc[4*c+1],
                                acc[4*c+2] + bc[4*c+2], acc[4*c+3] + bc[4*c+3]);
    }
}

// ---------------- fused aggregate (fp16 gather, window-sorted CSR) + combine ----------------
template<int LAYER2>
__global__ __launch_bounds__(256) void k_agg(
    const int* __restrict__ csr, const int2* __restrict__ sd,
    const __half* __restrict__ bsh, const float* __restrict__ dis,
    const float* __restrict__ wcomb, const float* __restrict__ bias,
    float* __restrict__ h,
    const float* __restrict__ Wcls, const float* __restrict__ bcls,
    float* __restrict__ p, int n)
{
    int wid = (blockIdx.x * 256 + threadIdx.x) >> 6;
    int lane = threadIdx.x & 63;
    if (wid >= n) return;
    int2 s2 = sd[wid];
    int start = s2.x, deg = s2.y;
    int g = lane >> 4, q = lane & 15;

    const uint2* bsp = (const uint2*)bsh;
    float4 acc4 = make_float4(0.f, 0.f, 0.f, 0.f);
    if (g == 0) {  // self-loop term (pre-scaled)
        uint2 v = bsp[(size_t)wid * 16 + q];
        float2 lo = __half22float2(*(const __half2*)&v.x);
        float2 hi = __half22float2(*(const __half2*)&v.y);
        acc4 = make_float4(lo.x, lo.y, hi.x, hi.y);
    }

    int j = 0;
    int ia = 0, ib = 0;
    if (8 <= deg) { ia = csr[start + g]; ib = csr[start + 4 + g]; }
    while (j + 8 <= deg) {
        int jn = j + 8;
        int na = 0, nb = 0;
        if (jn + 8 <= deg) { na = csr[start + jn + g]; nb = csr[start + jn + 4 + g]; }
        uint2 v0 = bsp[(size_t)ia * 16 + q];
        uint2 v1 = bsp[(size_t)ib * 16 + q];
        float2 l0 = __half22float2(*(const __half2*)&v0.x);
        float2 h0 = __half22float2(*(const __half2*)&v0.y);
        float2 l1 = __half22float2(*(const __half2*)&v1.x);
        float2 h1 = __half22float2(*(const __half2*)&v1.y);
        acc4.x += l0.x + l1.x;
        acc4.y += l0.y + l1.y;
        acc4.z += h0.x + h1.x;
        acc4.w += h0.y + h1.y;
        ia = na; ib = nb; j = jn;
    }
    int last = start + deg - 1;
    for (; j < deg; j += 4) {
        int idx = start + j + g;
        int r = csr[min(idx, last)];
        uint2 v = bsp[(size_t)r * 16 + q];
        float2 lo = __half22float2(*(const __half2*)&v.x);
        float2 hi = __half22float2(*(const __half2*)&v.y);
        float m = (j + g < deg) ? 1.f : 0.f;
        acc4.x = fmaf(lo.x, m, acc4.x);
        acc4.y = fmaf(lo.y, m, acc4.y);
        acc4.z = fmaf(hi.x, m, acc4.z);
        acc4.w = fmaf(hi.y, m, acc4.w);
    }

    acc4.x += __shfl_xor(acc4.x, 16, 64);
    acc4.y += __shfl_xor(acc4.y, 16, 64);
    acc4.z += __shfl_xor(acc4.z, 16, 64);
    acc4.w += __shfl_xor(acc4.w, 16, 64);
    acc4.x += __shfl_xor(acc4.x, 32, 64);
    acc4.y += __shfl_xor(acc4.y, 32, 64);
    acc4.z += __shfl_xor(acc4.z, 32, 64);
    acc4.w += __shfl_xor(acc4.w, 32, 64);

    float d = dis[wid];
    acc4.x *= d; acc4.y *= d; acc4.z *= d; acc4.w *= d;

    int src = lane >> 2;
    float t0 = __shfl(acc4.x, src, 64);
    float t1 = __shfl(acc4.y, src, 64);
    float t2 = __shfl(acc4.z, src, 64);
    float t3 = __shfl(acc4.w, src, 64);
    int c = lane & 3;
    float acc = (c == 0) ? t0 : (c == 1) ? t1 : (c == 2) ? t2 : t3;

    int fh = lane & 15;
    float a0 = __shfl(acc, fh, 64);
    float a1 = __shfl(acc, 16 + fh, 64);
    float a2 = __shfl(acc, 32 + fh, 64);
    float a3 = __shfl(acc, 48 + fh, 64);
    const float* wn = wcomb + (size_t)wid * 32;
    int hd = lane >> 4;
    float s1 = bias[lane];
    float s2v = bias[64 + lane];
    s1 = fmaf(wn[hd * 4 + 0], a0, s1);
    s1 = fmaf(wn[hd * 4 + 1], a1, s1);
    s1 = fmaf(wn[hd * 4 + 2], a2, s1);
    s1 = fmaf(wn[hd * 4 + 3], a3, s1);
    s2v = fmaf(wn[(4 + hd) * 4 + 0], a0, s2v);
    s2v = fmaf(wn[(4 + hd) * 4 + 1], a1, s2v);
    s2v = fmaf(wn[(4 + hd) * 4 + 2], a2, s2v);
    s2v = fmaf(wn[(4 + hd) * 4 + 3], a3, s2v);

    if (!LAYER2) {
        s1 = fmaxf(s1, 0.f);
        s2v = fmaxf(s2v, 0.f);
        h[(size_t)wid * 128 + lane] = s1;
        h[(size_t)wid * 128 + 64 + lane] = s2v;
    } else {
        float r0 = s1 * Wcls[lane * 2 + 0] + s2v * Wcls[(64 + lane) * 2 + 0];
        float r1 = s1 * Wcls[lane * 2 + 1] + s2v * Wcls[(64 + lane) * 2 + 1];
        float r2 = s1 * Wcls[(128 + lane) * 2 + 0] + s2v * Wcls[(192 + lane) * 2 + 0];
        float r3 = s1 * Wcls[(128 + lane) * 2 + 1] + s2v * Wcls[(192 + lane) * 2 + 1];
#pragma unroll
        for (int off = 32; off; off >>= 1) {
            r0 += __shfl_xor(r0, off, 64);
            r1 += __shfl_xor(r1, off, 64);
            r2 += __shfl_xor(r2, off, 64);
            r3 += __shfl_xor(r3, off, 64);
        }
        if (lane == 0) {
            p[wid * 4 + 0] = r0 + bcls[0];
            p[wid * 4 + 1] = r1 + bcls[1];
            p[wid * 4 + 2] = r2;
            p[wid * 4 + 3] = r3;
        }
    }
}

// ---------------- edge output: 2 edges/thread ----------------
__global__ void k_edge(const int* __restrict__ ei, const float* __restrict__ p,
                       float* __restrict__ out)
{
    int t = blockIdx.x * blockDim.x + threadIdx.x;
    if (t >= EE / 2) return;
    int2 rr = *(const int2*)(ei + 2 * t);
    int2 cc = *(const int2*)(ei + EE + 2 * t);
    float2 pt0 = *(const float2*)(p + rr.x * 4);
    float2 pt1 = *(const float2*)(p + rr.y * 4);
    float2 pb0 = *(const float2*)(p + cc.x * 4 + 2);
    float2 pb1 = *(const float2*)(p + cc.y * 4 + 2);
    float4 o;
    o.x = pt0.x + pb0.x;
    o.y = pt0.y + pb0.y;
    o.z = pt1.x + pb1.x;
    o.w = pt1.y + pb1.y;
    *(float4*)(out + (size_t)t * 4) = o;
}

extern "C" void kernel_launch(void* const* d_in, const int* in_sizes, int n_in,
                              void* d_out, int out_size, void* d_ws, size_t ws_size,
                              hipStream_t stream) {
    const float* x    = (const float*)d_in[0];
    const int*   ei   = (const int*)d_in[1];
    const float* Wb1  = (const float*)d_in[2];
    const float* Wc1  = (const float*)d_in[3];
    const float* bc1  = (const float*)d_in[4];
    const float* b1   = (const float*)d_in[5];
    const float* Wb2  = (const float*)d_in[6];
    const float* Wc2  = (const float*)d_in[7];
    const float* bc2  = (const float*)d_in[8];
    const float* b2   = (const float*)d_in[9];
    const float* Wcls = (const float*)d_in[10];
    const float* bcls = (const float*)d_in[11];
    float* out = (float*)d_out;

    char* ws = (char*)d_ws;
    size_t off = 0;
    auto alloc = [&](size_t bytes) {
        void* pp = ws + off;
        off += (bytes + 15) & ~(size_t)15;
        return pp;
    };

    float*  dis    = (float*)alloc(50048 * 4);
    __half* bsh    = (__half*)alloc((size_t)NN * 64 * 2);
    float*  wcomb  = (float*)alloc((size_t)NN * 32 * 4);
    float*  h      = (float*)alloc((size_t)NN * 128 * 4);
    float*  p      = (float*)alloc((size_t)NN * 4 * 4);
    int*    cnt    = (int*)alloc((size_t)NBUCK * 4);
    int*    sloc   = (int*)alloc((size_t)NBUCK * 4);
    int*    bstart = (int*)alloc((size_t)(NBUCK + 16) * 4);
    int*    bsum   = (int*)alloc(1024 * 4);
    int2*   sd     = (int2*)alloc((size_t)50048 * 8);
    int*    csr    = (int*)alloc((size_t)EE * 4);
    int*    rank   = (int*)alloc((size_t)EE * 4);

    const int B = 256;
    int gN   = (NN + B - 1) / B;   // 196
    int gN64 = (NN * 64) / B;      // 12500
    dim3 gG(gN, 3);

    // CSR build (window-sorted neighbor lists; shared by both layers)
    hipMemsetAsync(cnt, 0, (size_t)NBUCK * sizeof(int), stream);
    k_count<<<NB_E2, B, 0, stream>>>(ei, cnt, rank);
    k_scan1<<<NSB, 1024, 0, stream>>>(cnt, sloc, bsum, NBUCK);
    k_scan23<<<NSB, 1024, 0, stream>>>(sloc, bsum, bstart, NBUCK, NSB);
    k_fill<<<NCHUNK * 8 + NSD, B, 0, stream>>>(ei, rank, bstart, csr, sd, dis);

    // conv1
    k_gemm<<<gG, B, 0, stream>>>(x, Wb1, Wc1, bc1, dis, bsh, wcomb, NN);
    k_agg<0><<<gN64, B, 0, stream>>>(csr, sd, bsh, dis, wcomb, b1, h,
                                     Wcls, bcls, p, NN);

    // conv2 (+ fused edge-cls projection)
    k_gemm<<<gG, B, 0, stream>>>(h, Wb2, Wc2, bc2, dis, bsh, wcomb, NN);
    k_agg<1><<<gN64, B, 0, stream>>>(csr, sd, bsh, dis, wcomb, b2, h,
                                     Wcls, bcls, p, NN);

    // edge output
    k_edge<<<NB_E2, B, 0, stream>>>(ei, p, out);
}